// Round 10
// baseline (57.414 us; speedup 1.0000x reference)
//
#include <hip/hip_runtime.h>

typedef float f32x4 __attribute__((ext_vector_type(4)));
typedef _Float16 f16x8 __attribute__((ext_vector_type(8)));
typedef __fp16 fp16x2 __attribute__((ext_vector_type(2)));

#define NEG_SLOPE 0.2f
#define MASK_EPS 1e-8f

// ---------------------------------------------------------------------------
// Kernel 0 (tiny): W (f32 [k][n]) -> wTf16 (f16 [n][k]). 16384 elements.
// ---------------------------------------------------------------------------
__global__ __launch_bounds__(256) void gat_prep_w(
    const float* __restrict__ W, _Float16* __restrict__ wTf16) {
  const int idx = blockIdx.x * 256 + threadIdx.x;
  const int k = idx >> 7, n = idx & 127;
  wTf16[n * 128 + k] = (_Float16)W[idx];
}

// ---------------------------------------------------------------------------
// Kernel 1 (fused, 2048 blocks interleaved by bid&1):
//  even bid: pack (adj > eps) into transposed bitmask maskT[b][j][16 u32]
//            (coalesced full-line adj reads, BW/latency-heavy)
//  odd  bid: Wh = h @ W via f16 MFMA + scores (VALU/MFMA-heavy)
// Interleaving makes both co-resident so wh's compute fills mask's stalls.
// ---------------------------------------------------------------------------
__global__ __launch_bounds__(256, 4) void gat_fused_mask_wh(
    const float* __restrict__ adj, unsigned* __restrict__ maskT,
    const float* __restrict__ h, const _Float16* __restrict__ wTf16,
    const float* __restrict__ a, _Float16* __restrict__ whT,
    float* __restrict__ sIT, float* __restrict__ sJT) {
  const int tid = threadIdx.x;
  const int bid0 = blockIdx.x;

  if ((bid0 & 1) == 0) {
    // ---- mask path: block covers (b, jt of 64 j, ic of 128 i) ----
    const int mb = bid0 >> 1;          // 0..1023
    const int b = mb & 31, jt = (mb >> 5) & 7, ic = mb >> 8;
    const int jl = tid & 63;
    const int iw4 = tid >> 6;          // 0..3
    const int j = jt * 64 + jl;
    const int i0 = ic * 128 + iw4 * 32;
    const float* ap = adj + (size_t)b * 512 * 512 + (size_t)i0 * 512 + j;
    unsigned w = 0;
#pragma unroll
    for (int i = 0; i < 32; ++i)
      w |= (ap[(size_t)i * 512] > MASK_EPS ? 1u : 0u) << i;
    maskT[((size_t)b * 512 + j) * 16 + ic * 4 + iw4] = w;
    return;
  }

  // ---- wh path: 16 rows per block; 4 waves = 4 heads ----
  const int bid = bid0 >> 1;           // 0..1023
  const int w = tid >> 6;
  const int lane = tid & 63;
  const int nl = lane & 15;
  const int ig = lane >> 4;
  const int row0 = bid * 16;
  const int bb = row0 >> 9;
  const int iloc = row0 & 511;

  const float* hP = h + (size_t)(row0 + nl) * 128 + ig * 8;
  const _Float16* wP0 = wTf16 + (size_t)(w * 32 + nl) * 128 + ig * 8;
  const _Float16* wP1 = wTf16 + (size_t)(w * 32 + 16 + nl) * 128 + ig * 8;

  f32x4 acc0 = {0.f, 0.f, 0.f, 0.f};
  f32x4 acc1 = {0.f, 0.f, 0.f, 0.f};

#pragma unroll
  for (int kt = 0; kt < 4; ++kt) {
    f32x4 ha = *(const f32x4*)(hP + kt * 32);
    f32x4 hb = *(const f32x4*)(hP + kt * 32 + 4);
    union { fp16x2 h2[4]; f16x8 v; } af;
    af.h2[0] = __builtin_amdgcn_cvt_pkrtz(ha.x, ha.y);
    af.h2[1] = __builtin_amdgcn_cvt_pkrtz(ha.z, ha.w);
    af.h2[2] = __builtin_amdgcn_cvt_pkrtz(hb.x, hb.y);
    af.h2[3] = __builtin_amdgcn_cvt_pkrtz(hb.z, hb.w);
    const f16x8 b0 = *(const f16x8*)(wP0 + kt * 32);
    const f16x8 b1 = *(const f16x8*)(wP1 + kt * 32);
    acc0 = __builtin_amdgcn_mfma_f32_16x16x32_f16(af.v, b0, acc0, 0, 0, 0);
    acc1 = __builtin_amdgcn_mfma_f32_16x16x32_f16(af.v, b1, acc1, 0, 0, 0);
  }

  // per-head scores (full fp32 path)
  const float avS0 = a[w * 64 + nl];
  const float avS1 = a[w * 64 + 16 + nl];
  const float avD0 = a[w * 64 + 32 + nl];
  const float avD1 = a[w * 64 + 48 + nl];

  float si[4], sj[4];
#pragma unroll
  for (int reg = 0; reg < 4; ++reg) {
    si[reg] = acc0[reg] * avS0 + acc1[reg] * avS1;
    sj[reg] = acc0[reg] * avD0 + acc1[reg] * avD1;
#pragma unroll
    for (int off = 1; off < 16; off <<= 1) {
      si[reg] += __shfl_xor(si[reg], off, 64);
      sj[reg] += __shfl_xor(sj[reg], off, 64);
    }
  }
  if (nl == 0) {
    const int base = bb * 2048 + w * 512 + iloc + ig * 4;
#pragma unroll
    for (int reg = 0; reg < 4; ++reg) {
      sIT[base + reg] = si[reg];
      sJT[base + reg] = sj[reg];
    }
  }

  // whT f16 writes (C layout: row m = ig*4+reg -> i, col n = nl -> d)
  union { fp16x2 h2[2]; float2 f2; } p0, p1;
  p0.h2[0] = __builtin_amdgcn_cvt_pkrtz(acc0[0], acc0[1]);
  p0.h2[1] = __builtin_amdgcn_cvt_pkrtz(acc0[2], acc0[3]);
  p1.h2[0] = __builtin_amdgcn_cvt_pkrtz(acc1[0], acc1[1]);
  p1.h2[1] = __builtin_amdgcn_cvt_pkrtz(acc1[2], acc1[3]);
  _Float16* wout = whT + (size_t)bb * 128 * 512 + iloc + ig * 4;
  *(float2*)(wout + (size_t)(w * 32 + nl) * 512)      = p0.f2;
  *(float2*)(wout + (size_t)(w * 32 + 16 + nl) * 512) = p1.f2;
}

// ---------------------------------------------------------------------------
// Kernel 2: attention+aggregate (R6-proven). Zero LDS, zero barriers, zero
// adj traffic: lane preloads its 16 mask words (64B); main loop is
// L2-resident si/WhT fragment loads + exp/cvt VALU + MFMA. Full unroll.
// ---------------------------------------------------------------------------
__global__ __launch_bounds__(256, 4) void gat_attn_kernel(
    const unsigned* __restrict__ maskT, const _Float16* __restrict__ whT,
    const float* __restrict__ sIT, const float* __restrict__ sJT,
    float* __restrict__ out) {
  const int tid = threadIdx.x;
  const int b = blockIdx.x;            // 0..31 (fast-varying)
  const int j0 = blockIdx.y * 16;      // 32 tiles
  const int wv = tid >> 6;             // wave = head
  const int lane = tid & 63;
  const int nl = lane & 15;
  const int ig = lane >> 4;

  const float sj = sJT[b * 2048 + wv * 512 + j0 + nl];

  const unsigned* mP = maskT + ((size_t)b * 512 + j0 + nl) * 16;
  uint4 mA = *(const uint4*)(mP);
  uint4 mB = *(const uint4*)(mP + 4);
  uint4 mC = *(const uint4*)(mP + 8);
  uint4 mD = *(const uint4*)(mP + 12);
  const unsigned mw[16] = {mA.x, mA.y, mA.z, mA.w, mB.x, mB.y, mB.z, mB.w,
                           mC.x, mC.y, mC.z, mC.w, mD.x, mD.y, mD.z, mD.w};

  const _Float16* whP = whT + (size_t)b * 128 * 512 + (size_t)(wv * 32 + nl) * 512 + ig * 8;
  const float* siP = sIT + b * 2048 + wv * 512 + ig * 8;

  f32x4 acc0 = {0.f, 0.f, 0.f, 0.f};
  f32x4 acc1 = {0.f, 0.f, 0.f, 0.f};
  float l = 0.f;

#pragma unroll
  for (int t = 0; t < 8; ++t) {
#pragma unroll
    for (int ks = 0; ks < 2; ++ks) {
      f32x4 sA = *(const f32x4*)(siP + t * 64 + ks * 32);
      f32x4 sB = *(const f32x4*)(siP + t * 64 + ks * 32 + 4);
      const f16x8 bf0 = *(const f16x8*)(whP + t * 64 + ks * 32);
      const f16x8 bf1 = *(const f16x8*)(whP + 16 * 512 + t * 64 + ks * 32);
      const unsigned bits = (mw[t * 2 + ks] >> (ig * 8)) & 0xffu;

      float si[8] = {sA.x, sA.y, sA.z, sA.w, sB.x, sB.y, sB.z, sB.w};
      float p[8];
#pragma unroll
      for (int r = 0; r < 8; ++r) {
        float e = si[r] + sj;
        e = e >= 0.f ? e : NEG_SLOPE * e;
        p[r] = (bits & (1u << r)) ? __expf(e) : 0.f;
      }
      l += ((p[0] + p[1]) + (p[2] + p[3])) + ((p[4] + p[5]) + (p[6] + p[7]));

      union { fp16x2 h2[4]; f16x8 v; } af;
#pragma unroll
      for (int q = 0; q < 4; ++q)
        af.h2[q] = __builtin_amdgcn_cvt_pkrtz(p[2 * q], p[2 * q + 1]);

      acc0 = __builtin_amdgcn_mfma_f32_16x16x32_f16(af.v, bf0, acc0, 0, 0, 0);
      acc1 = __builtin_amdgcn_mfma_f32_16x16x32_f16(af.v, bf1, acc1, 0, 0, 0);
    }
  }

  // reduce l over the 4 ig-slices -> every lane has l for j = j0 + nl
  l += __shfl_xor(l, 16, 64);
  l += __shfl_xor(l, 32, 64);

  // D layout: row(m=j_local) = 4*ig + reg, col(n=d_lo) = nl
  float* outB = out + ((size_t)b * 512 + j0) * 128 + wv * 32;
#pragma unroll
  for (int reg = 0; reg < 4; ++reg) {
    const int jr = 4 * ig + reg;
    const float rl = 1.0f / __shfl(l, jr, 64);
    outB[(size_t)jr * 128 + nl]      = acc0[reg] * rl;
    outB[(size_t)jr * 128 + 16 + nl] = acc1[reg] * rl;
  }
}

extern "C" void kernel_launch(void* const* d_in, const int* in_sizes, int n_in,
                              void* d_out, int out_size, void* d_ws, size_t ws_size,
                              hipStream_t stream) {
  const float* h = (const float*)d_in[0];     // (32, 512, 128)
  const float* adj = (const float*)d_in[1];   // (32, 512, 512)
  const float* W = (const float*)d_in[2];     // (128, 128)
  const float* a = (const float*)d_in[3];     // (4, 64)
  float* out = (float*)d_out;                 // (32, 512, 128)

  _Float16* whT = (_Float16*)d_ws;                      // 4 MB
  float* sIT = (float*)(whT + (size_t)32 * 128 * 512);  // 256 KB
  float* sJT = sIT + (size_t)32 * 4 * 512;              // 256 KB
  unsigned* maskT = (unsigned*)(sJT + (size_t)32 * 4 * 512);      // 1 MB
  _Float16* wTf16 = (_Float16*)(maskT + (size_t)32 * 512 * 16);   // 32 KB

  gat_prep_w<<<dim3(64), dim3(256), 0, stream>>>(W, wTf16);
  gat_fused_mask_wh<<<dim3(2048), dim3(256), 0, stream>>>(
      adj, maskT, h, wTf16, a, whT, sIT, sJT);
  gat_attn_kernel<<<dim3(32, 32), dim3(256), 0, stream>>>(maskT, whT, sIT, sJT, out);
}

// Round 11
// 52.072 us; speedup vs baseline: 1.1026x; 1.1026x over previous
//
#include <hip/hip_runtime.h>

typedef float f32x4 __attribute__((ext_vector_type(4)));
typedef _Float16 f16x8 __attribute__((ext_vector_type(8)));
typedef __fp16 fp16x2 __attribute__((ext_vector_type(2)));

#define NEG_SLOPE 0.2f
#define MASK_EPS 1e-8f

// ---------------------------------------------------------------------------
// Kernel 1: pack (adj > eps) into transposed bitmask maskT[b][j][16 u32]
// (bit i%32 of word i/32). Coalesced adj reads. Blocks with jt==0&&ic==0 also
// convert W (f32 [k][n]) -> wTf16 (f16 [n][k]).  (R6-proven, verbatim)
// ---------------------------------------------------------------------------
__global__ __launch_bounds__(256) void gat_mask_kernel(
    const float* __restrict__ adj, unsigned* __restrict__ maskT,
    const float* __restrict__ W, _Float16* __restrict__ wTf16) {
  const int b = blockIdx.x, jt = blockIdx.y, ic = blockIdx.z;
  const int tid = threadIdx.x;
  const int jl = tid & 63;
  const int iw4 = tid >> 6;            // 0..3
  const int j = jt * 64 + jl;
  const int i0 = ic * 128 + iw4 * 32;
  const float* ap = adj + (size_t)b * 512 * 512 + (size_t)i0 * 512 + j;
  unsigned w = 0;
#pragma unroll
  for (int i = 0; i < 32; ++i)
    w |= (ap[(size_t)i * 512] > MASK_EPS ? 1u : 0u) << i;
  maskT[((size_t)b * 512 + j) * 16 + ic * 4 + iw4] = w;

  if (jt == 0 && ic == 0) {            // 32 blocks: W transpose+convert
    const int k = b * 4 + (tid >> 6);  // 4 k-rows per block
    const int n = tid & 63;
    wTf16[(n) * 128 + k]      = (_Float16)W[k * 128 + n];
    wTf16[(n + 64) * 128 + k] = (_Float16)W[k * 128 + n + 64];
  }
}

// ---------------------------------------------------------------------------
// Kernel 2: Wh = h @ W via f16 MFMA. Zero LDS, zero barriers. (R7-proven)
// Block = 16 rows; 4 waves = 4 heads (n-quarters of 32 cols).
// ---------------------------------------------------------------------------
__global__ __launch_bounds__(256, 4) void gat_wh_mfma(
    const float* __restrict__ h, const _Float16* __restrict__ wTf16,
    const float* __restrict__ a, _Float16* __restrict__ whT,
    float* __restrict__ sIT, float* __restrict__ sJT) {
  const int tid = threadIdx.x;
  const int bid = blockIdx.x;          // 0..1023, 16 rows each
  const int w = tid >> 6;              // wave = head
  const int lane = tid & 63;
  const int nl = lane & 15;
  const int ig = lane >> 4;
  const int row0 = bid * 16;
  const int bb = row0 >> 9;
  const int iloc = row0 & 511;

  const float* hP = h + (size_t)(row0 + nl) * 128 + ig * 8;
  const _Float16* wP0 = wTf16 + (size_t)(w * 32 + nl) * 128 + ig * 8;
  const _Float16* wP1 = wTf16 + (size_t)(w * 32 + 16 + nl) * 128 + ig * 8;

  f32x4 acc0 = {0.f, 0.f, 0.f, 0.f};
  f32x4 acc1 = {0.f, 0.f, 0.f, 0.f};

#pragma unroll
  for (int kt = 0; kt < 4; ++kt) {
    f32x4 ha = *(const f32x4*)(hP + kt * 32);
    f32x4 hb = *(const f32x4*)(hP + kt * 32 + 4);
    union { fp16x2 h2[4]; f16x8 v; } af;
    af.h2[0] = __builtin_amdgcn_cvt_pkrtz(ha.x, ha.y);
    af.h2[1] = __builtin_amdgcn_cvt_pkrtz(ha.z, ha.w);
    af.h2[2] = __builtin_amdgcn_cvt_pkrtz(hb.x, hb.y);
    af.h2[3] = __builtin_amdgcn_cvt_pkrtz(hb.z, hb.w);
    const f16x8 b0 = *(const f16x8*)(wP0 + kt * 32);
    const f16x8 b1 = *(const f16x8*)(wP1 + kt * 32);
    acc0 = __builtin_amdgcn_mfma_f32_16x16x32_f16(af.v, b0, acc0, 0, 0, 0);
    acc1 = __builtin_amdgcn_mfma_f32_16x16x32_f16(af.v, b1, acc1, 0, 0, 0);
  }

  // ---- per-head scores (full fp32 path) ----
  const float avS0 = a[w * 64 + nl];
  const float avS1 = a[w * 64 + 16 + nl];
  const float avD0 = a[w * 64 + 32 + nl];
  const float avD1 = a[w * 64 + 48 + nl];

  float si[4], sj[4];
#pragma unroll
  for (int reg = 0; reg < 4; ++reg) {
    si[reg] = acc0[reg] * avS0 + acc1[reg] * avS1;
    sj[reg] = acc0[reg] * avD0 + acc1[reg] * avD1;
#pragma unroll
    for (int off = 1; off < 16; off <<= 1) {
      si[reg] += __shfl_xor(si[reg], off, 64);
      sj[reg] += __shfl_xor(sj[reg], off, 64);
    }
  }
  if (nl == 0) {
    const int base = bb * 2048 + w * 512 + iloc + ig * 4;
#pragma unroll
    for (int reg = 0; reg < 4; ++reg) {
      sIT[base + reg] = si[reg];
      sJT[base + reg] = sj[reg];
    }
  }

  // ---- whT f16 writes (C layout: row m = ig*4+reg -> i, col n = nl -> d) ----
  union { fp16x2 h2[2]; float2 f2; } p0, p1;
  p0.h2[0] = __builtin_amdgcn_cvt_pkrtz(acc0[0], acc0[1]);
  p0.h2[1] = __builtin_amdgcn_cvt_pkrtz(acc0[2], acc0[3]);
  p1.h2[0] = __builtin_amdgcn_cvt_pkrtz(acc1[0], acc1[1]);
  p1.h2[1] = __builtin_amdgcn_cvt_pkrtz(acc1[2], acc1[3]);
  _Float16* wout = whT + (size_t)bb * 128 * 512 + iloc + ig * 4;
  *(float2*)(wout + (size_t)(w * 32 + nl) * 512)      = p0.f2;
  *(float2*)(wout + (size_t)(w * 32 + 16 + nl) * 512) = p1.f2;
}

// ---------------------------------------------------------------------------
// Kernel 3: attention+aggregate (R6-proven). Zero LDS, zero barriers, zero
// adj traffic: lane preloads its 16 mask words (64B); main loop is
// L2-resident si/WhT fragment loads + exp/cvt VALU + MFMA. Full unroll.
// ---------------------------------------------------------------------------
__global__ __launch_bounds__(256, 4) void gat_attn_kernel(
    const unsigned* __restrict__ maskT, const _Float16* __restrict__ whT,
    const float* __restrict__ sIT, const float* __restrict__ sJT,
    float* __restrict__ out) {
  const int tid = threadIdx.x;
  const int b = blockIdx.x;            // 0..31 (fast-varying)
  const int j0 = blockIdx.y * 16;      // 32 tiles
  const int wv = tid >> 6;             // wave = head
  const int lane = tid & 63;
  const int nl = lane & 15;
  const int ig = lane >> 4;

  const float sj = sJT[b * 2048 + wv * 512 + j0 + nl];

  const unsigned* mP = maskT + ((size_t)b * 512 + j0 + nl) * 16;
  uint4 mA = *(const uint4*)(mP);
  uint4 mB = *(const uint4*)(mP + 4);
  uint4 mC = *(const uint4*)(mP + 8);
  uint4 mD = *(const uint4*)(mP + 12);
  const unsigned mw[16] = {mA.x, mA.y, mA.z, mA.w, mB.x, mB.y, mB.z, mB.w,
                           mC.x, mC.y, mC.z, mC.w, mD.x, mD.y, mD.z, mD.w};

  const _Float16* whP = whT + (size_t)b * 128 * 512 + (size_t)(wv * 32 + nl) * 512 + ig * 8;
  const float* siP = sIT + b * 2048 + wv * 512 + ig * 8;

  f32x4 acc0 = {0.f, 0.f, 0.f, 0.f};
  f32x4 acc1 = {0.f, 0.f, 0.f, 0.f};
  float l = 0.f;

#pragma unroll
  for (int t = 0; t < 8; ++t) {
#pragma unroll
    for (int ks = 0; ks < 2; ++ks) {
      f32x4 sA = *(const f32x4*)(siP + t * 64 + ks * 32);
      f32x4 sB = *(const f32x4*)(siP + t * 64 + ks * 32 + 4);
      const f16x8 bf0 = *(const f16x8*)(whP + t * 64 + ks * 32);
      const f16x8 bf1 = *(const f16x8*)(whP + 16 * 512 + t * 64 + ks * 32);
      const unsigned bits = (mw[t * 2 + ks] >> (ig * 8)) & 0xffu;

      float si[8] = {sA.x, sA.y, sA.z, sA.w, sB.x, sB.y, sB.z, sB.w};
      float p[8];
#pragma unroll
      for (int r = 0; r < 8; ++r) {
        float e = si[r] + sj;
        e = e >= 0.f ? e : NEG_SLOPE * e;
        p[r] = (bits & (1u << r)) ? __expf(e) : 0.f;
      }
      l += ((p[0] + p[1]) + (p[2] + p[3])) + ((p[4] + p[5]) + (p[6] + p[7]));

      union { fp16x2 h2[4]; f16x8 v; } af;
#pragma unroll
      for (int q = 0; q < 4; ++q)
        af.h2[q] = __builtin_amdgcn_cvt_pkrtz(p[2 * q], p[2 * q + 1]);

      acc0 = __builtin_amdgcn_mfma_f32_16x16x32_f16(af.v, bf0, acc0, 0, 0, 0);
      acc1 = __builtin_amdgcn_mfma_f32_16x16x32_f16(af.v, bf1, acc1, 0, 0, 0);
    }
  }

  // reduce l over the 4 ig-slices -> every lane has l for j = j0 + nl
  l += __shfl_xor(l, 16, 64);
  l += __shfl_xor(l, 32, 64);

  // D layout: row(m=j_local) = 4*ig + reg, col(n=d_lo) = nl
  float* outB = out + ((size_t)b * 512 + j0) * 128 + wv * 32;
#pragma unroll
  for (int reg = 0; reg < 4; ++reg) {
    const int jr = 4 * ig + reg;
    const float rl = 1.0f / __shfl(l, jr, 64);
    outB[(size_t)jr * 128 + nl]      = acc0[reg] * rl;
    outB[(size_t)jr * 128 + 16 + nl] = acc1[reg] * rl;
  }
}

extern "C" void kernel_launch(void* const* d_in, const int* in_sizes, int n_in,
                              void* d_out, int out_size, void* d_ws, size_t ws_size,
                              hipStream_t stream) {
  const float* h = (const float*)d_in[0];     // (32, 512, 128)
  const float* adj = (const float*)d_in[1];   // (32, 512, 512)
  const float* W = (const float*)d_in[2];     // (128, 128)
  const float* a = (const float*)d_in[3];     // (4, 64)
  float* out = (float*)d_out;                 // (32, 512, 128)

  _Float16* whT = (_Float16*)d_ws;                      // 4 MB
  float* sIT = (float*)(whT + (size_t)32 * 128 * 512);  // 256 KB
  float* sJT = sIT + (size_t)32 * 4 * 512;              // 256 KB
  unsigned* maskT = (unsigned*)(sJT + (size_t)32 * 4 * 512);      // 1 MB
  _Float16* wTf16 = (_Float16*)(maskT + (size_t)32 * 512 * 16);   // 32 KB

  gat_mask_kernel<<<dim3(32, 8, 4), dim3(256), 0, stream>>>(adj, maskT, W, wTf16);
  gat_wh_mfma<<<dim3(1024), dim3(256), 0, stream>>>(h, wTf16, a, whT, sIT, sJT);
  gat_attn_kernel<<<dim3(32, 32), dim3(256), 0, stream>>>(maskT, whT, sIT, sJT, out);
}

// Round 12
// 46.716 us; speedup vs baseline: 1.2290x; 1.1147x over previous
//
#include <hip/hip_runtime.h>

typedef float f32x4 __attribute__((ext_vector_type(4)));
typedef _Float16 f16x8 __attribute__((ext_vector_type(8)));
typedef __fp16 fp16x2 __attribute__((ext_vector_type(2)));

#define NEG_SLOPE 0.2f
#define MASK_EPS 1e-8f

// ---------------------------------------------------------------------------
// Kernel 1: pack (adj > eps) into transposed bitmask maskT[b][j][16 u32],
// float2-vectorized (thread packs 2 j-columns, 32 x 8B unrolled loads).
// Blocks with ic==0 also convert W -> wTf16 (f16 [n][k]).
// ---------------------------------------------------------------------------
__global__ __launch_bounds__(256) void gat_mask_kernel(
    const float* __restrict__ adj, unsigned* __restrict__ maskT,
    const float* __restrict__ W, _Float16* __restrict__ wTf16) {
  const int b = blockIdx.x;            // 0..31
  const int ic = blockIdx.y;           // 0..15: 32-i word index
  const int tid = threadIdx.x;
  const int j = tid * 2;
  const float* ap = adj + (size_t)b * 262144 + (size_t)ic * 32 * 512 + j;
  unsigned w0 = 0, w1 = 0;
#pragma unroll
  for (int i = 0; i < 32; ++i) {
    float2 v = *(const float2*)(ap + (size_t)i * 512);
    w0 |= (v.x > MASK_EPS ? 1u : 0u) << i;
    w1 |= (v.y > MASK_EPS ? 1u : 0u) << i;
  }
  unsigned* mp = maskT + ((size_t)b * 512 + j) * 16 + ic;
  mp[0] = w0;
  mp[16] = w1;

  if (ic == 0) {                       // 32 blocks: W transpose+convert
    const int k = b * 4 + (tid >> 6);
    const int n = tid & 63;
    wTf16[(n) * 128 + k]      = (_Float16)W[k * 128 + n];
    wTf16[(n + 64) * 128 + k] = (_Float16)W[k * 128 + n + 64];
  }
}

// ---------------------------------------------------------------------------
// Kernel 2: Wh = h @ W via f16 MFMA. Zero LDS, zero barriers. (R7-proven)
// ---------------------------------------------------------------------------
__global__ __launch_bounds__(256, 4) void gat_wh_mfma(
    const float* __restrict__ h, const _Float16* __restrict__ wTf16,
    const float* __restrict__ a, _Float16* __restrict__ whT,
    float* __restrict__ sIT, float* __restrict__ sJT) {
  const int tid = threadIdx.x;
  const int bid = blockIdx.x;          // 0..1023, 16 rows each
  const int w = tid >> 6;              // wave = head
  const int lane = tid & 63;
  const int nl = lane & 15;
  const int ig = lane >> 4;
  const int row0 = bid * 16;
  const int bb = row0 >> 9;
  const int iloc = row0 & 511;

  const float* hP = h + (size_t)(row0 + nl) * 128 + ig * 8;
  const _Float16* wP0 = wTf16 + (size_t)(w * 32 + nl) * 128 + ig * 8;
  const _Float16* wP1 = wTf16 + (size_t)(w * 32 + 16 + nl) * 128 + ig * 8;

  f32x4 acc0 = {0.f, 0.f, 0.f, 0.f};
  f32x4 acc1 = {0.f, 0.f, 0.f, 0.f};

#pragma unroll
  for (int kt = 0; kt < 4; ++kt) {
    f32x4 ha = *(const f32x4*)(hP + kt * 32);
    f32x4 hb = *(const f32x4*)(hP + kt * 32 + 4);
    union { fp16x2 h2[4]; f16x8 v; } af;
    af.h2[0] = __builtin_amdgcn_cvt_pkrtz(ha.x, ha.y);
    af.h2[1] = __builtin_amdgcn_cvt_pkrtz(ha.z, ha.w);
    af.h2[2] = __builtin_amdgcn_cvt_pkrtz(hb.x, hb.y);
    af.h2[3] = __builtin_amdgcn_cvt_pkrtz(hb.z, hb.w);
    const f16x8 b0 = *(const f16x8*)(wP0 + kt * 32);
    const f16x8 b1 = *(const f16x8*)(wP1 + kt * 32);
    acc0 = __builtin_amdgcn_mfma_f32_16x16x32_f16(af.v, b0, acc0, 0, 0, 0);
    acc1 = __builtin_amdgcn_mfma_f32_16x16x32_f16(af.v, b1, acc1, 0, 0, 0);
  }

  const float avS0 = a[w * 64 + nl];
  const float avS1 = a[w * 64 + 16 + nl];
  const float avD0 = a[w * 64 + 32 + nl];
  const float avD1 = a[w * 64 + 48 + nl];

  float si[4], sj[4];
#pragma unroll
  for (int reg = 0; reg < 4; ++reg) {
    si[reg] = acc0[reg] * avS0 + acc1[reg] * avS1;
    sj[reg] = acc0[reg] * avD0 + acc1[reg] * avD1;
#pragma unroll
    for (int off = 1; off < 16; off <<= 1) {
      si[reg] += __shfl_xor(si[reg], off, 64);
      sj[reg] += __shfl_xor(sj[reg], off, 64);
    }
  }
  if (nl == 0) {
    const int base = bb * 2048 + w * 512 + iloc + ig * 4;
#pragma unroll
    for (int reg = 0; reg < 4; ++reg) {
      sIT[base + reg] = si[reg];
      sJT[base + reg] = sj[reg];
    }
  }

  union { fp16x2 h2[2]; float2 f2; } p0, p1;
  p0.h2[0] = __builtin_amdgcn_cvt_pkrtz(acc0[0], acc0[1]);
  p0.h2[1] = __builtin_amdgcn_cvt_pkrtz(acc0[2], acc0[3]);
  p1.h2[0] = __builtin_amdgcn_cvt_pkrtz(acc1[0], acc1[1]);
  p1.h2[1] = __builtin_amdgcn_cvt_pkrtz(acc1[2], acc1[3]);
  _Float16* wout = whT + (size_t)bb * 128 * 512 + iloc + ig * 4;
  *(float2*)(wout + (size_t)(w * 32 + nl) * 512)      = p0.f2;
  *(float2*)(wout + (size_t)(w * 32 + 16 + nl) * 512) = p1.f2;
}

// ---------------------------------------------------------------------------
// Kernel 3: attention+aggregate. Block = 512 thr = 8 waves = 4 heads x 2
// i-halves; j-tile 32 (each bf/si load feeds 4 MFMAs). Mask bits in regs,
// si/WhT direct from L2/IF. i-halves merged via one LDS exchange + barrier
// (l and acc are additive: no max-subtraction). Division + store by half-0.
// ---------------------------------------------------------------------------
__global__ __launch_bounds__(512, 4) void gat_attn_kernel(
    const unsigned* __restrict__ maskT, const _Float16* __restrict__ whT,
    const float* __restrict__ sIT, const float* __restrict__ sJT,
    float* __restrict__ out) {
  __shared__ float ldsA[4][64][17];    // [head][lane][16 acc + pad]
  __shared__ float ldsL[4][2][64];

  const int tid = threadIdx.x;
  const int b = blockIdx.x;            // 0..31 (fast dim: same-b = same XCD)
  const int j0 = blockIdx.y * 32;      // 16 tiles
  const int w8 = tid >> 6;             // 0..7
  const int hd = w8 & 3;               // head
  const int ih = w8 >> 2;              // i-half
  const int lane = tid & 63;
  const int nl = lane & 15;
  const int ig = lane >> 4;

  const float sj0 = sJT[b * 2048 + hd * 512 + j0 + nl];
  const float sj1 = sJT[b * 2048 + hd * 512 + j0 + 16 + nl];

  const unsigned* mP0 = maskT + ((size_t)b * 512 + j0 + nl) * 16 + ih * 8;
  const unsigned* mP1 = maskT + ((size_t)b * 512 + j0 + 16 + nl) * 16 + ih * 8;
  uint4 mA = *(const uint4*)(mP0);
  uint4 mB = *(const uint4*)(mP0 + 4);
  uint4 mC = *(const uint4*)(mP1);
  uint4 mD = *(const uint4*)(mP1 + 4);
  const unsigned mw0[8] = {mA.x, mA.y, mA.z, mA.w, mB.x, mB.y, mB.z, mB.w};
  const unsigned mw1[8] = {mC.x, mC.y, mC.z, mC.w, mD.x, mD.y, mD.z, mD.w};

  const _Float16* whP = whT + (size_t)b * 65536 + (size_t)(hd * 32 + nl) * 512 + ih * 256 + ig * 8;
  const float* siP = sIT + b * 2048 + hd * 512 + ih * 256 + ig * 8;

  f32x4 acc00 = {0.f, 0.f, 0.f, 0.f}, acc01 = {0.f, 0.f, 0.f, 0.f};
  f32x4 acc10 = {0.f, 0.f, 0.f, 0.f}, acc11 = {0.f, 0.f, 0.f, 0.f};
  float l0 = 0.f, l1 = 0.f;

#pragma unroll
  for (int t = 0; t < 4; ++t) {
#pragma unroll
    for (int ks = 0; ks < 2; ++ks) {
      const int idx = t * 64 + ks * 32;
      f32x4 sA = *(const f32x4*)(siP + idx);
      f32x4 sB = *(const f32x4*)(siP + idx + 4);
      const f16x8 bf0 = *(const f16x8*)(whP + idx);
      const f16x8 bf1 = *(const f16x8*)(whP + 16 * 512 + idx);
      const unsigned bits0 = (mw0[t * 2 + ks] >> (ig * 8)) & 0xffu;
      const unsigned bits1 = (mw1[t * 2 + ks] >> (ig * 8)) & 0xffu;

      float si[8] = {sA.x, sA.y, sA.z, sA.w, sB.x, sB.y, sB.z, sB.w};
      float p0[8], p1[8];
#pragma unroll
      for (int r = 0; r < 8; ++r) {
        float e0 = si[r] + sj0;
        e0 = e0 >= 0.f ? e0 : NEG_SLOPE * e0;
        p0[r] = (bits0 & (1u << r)) ? __expf(e0) : 0.f;
        float e1 = si[r] + sj1;
        e1 = e1 >= 0.f ? e1 : NEG_SLOPE * e1;
        p1[r] = (bits1 & (1u << r)) ? __expf(e1) : 0.f;
      }
      l0 += ((p0[0] + p0[1]) + (p0[2] + p0[3])) + ((p0[4] + p0[5]) + (p0[6] + p0[7]));
      l1 += ((p1[0] + p1[1]) + (p1[2] + p1[3])) + ((p1[4] + p1[5]) + (p1[6] + p1[7]));

      union { fp16x2 h2[4]; f16x8 v; } af0, af1;
#pragma unroll
      for (int q = 0; q < 4; ++q) {
        af0.h2[q] = __builtin_amdgcn_cvt_pkrtz(p0[2 * q], p0[2 * q + 1]);
        af1.h2[q] = __builtin_amdgcn_cvt_pkrtz(p1[2 * q], p1[2 * q + 1]);
      }

      acc00 = __builtin_amdgcn_mfma_f32_16x16x32_f16(af0.v, bf0, acc00, 0, 0, 0);
      acc01 = __builtin_amdgcn_mfma_f32_16x16x32_f16(af0.v, bf1, acc01, 0, 0, 0);
      acc10 = __builtin_amdgcn_mfma_f32_16x16x32_f16(af1.v, bf0, acc10, 0, 0, 0);
      acc11 = __builtin_amdgcn_mfma_f32_16x16x32_f16(af1.v, bf1, acc11, 0, 0, 0);
    }
  }

  // reduce l over the 4 ig-slices (within wave)
  l0 += __shfl_xor(l0, 16, 64); l0 += __shfl_xor(l0, 32, 64);
  l1 += __shfl_xor(l1, 16, 64); l1 += __shfl_xor(l1, 32, 64);

  // ---- merge i-halves via LDS (waves 4..7 publish, 0..3 absorb) ----
  if (ih == 1) {
    float* dst = &ldsA[hd][lane][0];
#pragma unroll
    for (int q = 0; q < 4; ++q) {
      dst[q] = acc00[q]; dst[4 + q] = acc01[q];
      dst[8 + q] = acc10[q]; dst[12 + q] = acc11[q];
    }
    ldsL[hd][0][lane] = l0;
    ldsL[hd][1][lane] = l1;
  }
  __syncthreads();
  if (ih == 0) {
    const float* src = &ldsA[hd][lane][0];
#pragma unroll
    for (int q = 0; q < 4; ++q) {
      acc00[q] += src[q]; acc01[q] += src[4 + q];
      acc10[q] += src[8 + q]; acc11[q] += src[12 + q];
    }
    const float lt0 = l0 + ldsL[hd][0][lane];
    const float lt1 = l1 + ldsL[hd][1][lane];

    float* outB = out + ((size_t)b * 512 + j0) * 128 + hd * 32;
#pragma unroll
    for (int reg = 0; reg < 4; ++reg) {
      const int jr = 4 * ig + reg;
      const float rl0 = 1.0f / __shfl(lt0, jr, 64);
      const float rl1 = 1.0f / __shfl(lt1, jr, 64);
      outB[(size_t)jr * 128 + nl]             = acc00[reg] * rl0;
      outB[(size_t)jr * 128 + 16 + nl]        = acc01[reg] * rl0;
      outB[(size_t)(16 + jr) * 128 + nl]      = acc10[reg] * rl1;
      outB[(size_t)(16 + jr) * 128 + 16 + nl] = acc11[reg] * rl1;
    }
  }
}

extern "C" void kernel_launch(void* const* d_in, const int* in_sizes, int n_in,
                              void* d_out, int out_size, void* d_ws, size_t ws_size,
                              hipStream_t stream) {
  const float* h = (const float*)d_in[0];     // (32, 512, 128)
  const float* adj = (const float*)d_in[1];   // (32, 512, 512)
  const float* W = (const float*)d_in[2];     // (128, 128)
  const float* a = (const float*)d_in[3];     // (4, 64)
  float* out = (float*)d_out;                 // (32, 512, 128)

  _Float16* whT = (_Float16*)d_ws;                      // 4 MB
  float* sIT = (float*)(whT + (size_t)32 * 128 * 512);  // 256 KB
  float* sJT = sIT + (size_t)32 * 4 * 512;              // 256 KB
  unsigned* maskT = (unsigned*)(sJT + (size_t)32 * 4 * 512);      // 1 MB
  _Float16* wTf16 = (_Float16*)(maskT + (size_t)32 * 512 * 16);   // 32 KB

  gat_mask_kernel<<<dim3(32, 16), dim3(256), 0, stream>>>(adj, maskT, W, wTf16);
  gat_wh_mfma<<<dim3(1024), dim3(256), 0, stream>>>(h, wTf16, a, whT, sIT, sJT);
  gat_attn_kernel<<<dim3(32, 16), dim3(512), 0, stream>>>(maskT, whT, sIT, sJT, out);
}